// Round 11
// baseline (114.969 us; speedup 1.0000x reference)
//
#include <hip/hip_runtime.h>
#include <math.h>

#define NB 4096   // batch
#define NS 64     // seq
#define NF 8      // feat
#define ND 64     // d_model
#define KL 512    // GEMM K = NS*NF (rank-8 trick)
#define NK 16     // top-k

typedef _Float16 half8 __attribute__((ext_vector_type(8)));
typedef float    f32x4 __attribute__((ext_vector_type(4)));

#define GLD16(src, dst) \
  __builtin_amdgcn_global_load_lds((const __attribute__((address_space(1))) void*)(src), \
                                   (__attribute__((address_space(3))) void*)(dst), 16, 0, 0)

#define WAITVM(N) asm volatile("s_waitcnt vmcnt(" #N ")" ::: "memory")

// ---------------- block reduce helper ----------------
__device__ __forceinline__ float blk_reduce(float v, float* red) {
    #pragma unroll
    for (int o = 32; o > 0; o >>= 1) v += __shfl_down(v, o, 64);
    const int t = threadIdx.x;
    __syncthreads();
    if ((t & 63) == 0) red[t >> 6] = v;
    __syncthreads();
    float r = 0.f;
    if (t == 0) r = red[0] + red[1] + red[2] + red[3];
    return r;
}

// ---- consts: G = We@We^T [8x8], M = We@Wp [8x8], u = We@be [8], c8 = be@Wp + bp [8] ----
__global__ __launch_bounds__(64) void consts_kernel(
    const float* __restrict__ Wemb, const float* __restrict__ bemb,
    const float* __restrict__ Wp, const float* __restrict__ bp, float* __restrict__ cst)
{
    __shared__ float sWe[NF * ND];   // [f][d]
    __shared__ float sWp[ND * NF];   // [d][f]
    __shared__ float sbe[ND];
    __shared__ float sbp[NF];
    const int t = threadIdx.x;
    #pragma unroll
    for (int i = 0; i < 8; ++i) { sWe[t + i * 64] = Wemb[t + i * 64]; sWp[t + i * 64] = Wp[t + i * 64]; }
    sbe[t] = bemb[t];
    if (t < NF) sbp[t] = bp[t];
    __syncthreads();
    const int f = t >> 3, f2 = t & 7;
    float g = 0.f, m = 0.f;
    #pragma unroll
    for (int d = 0; d < ND; ++d) {
        g += sWe[f * ND + d] * sWe[f2 * ND + d];
        m += sWe[f * ND + d] * sWp[d * NF + f2];
    }
    cst[t] = g;          // G[f][f2]
    cst[64 + t] = m;     // M[f][f2]
    if (t < NF) {
        float uu = 0.f, cc = 0.f;
        #pragma unroll
        for (int d = 0; d < ND; ++d) {
            uu += sWe[t * ND + d] * sbe[d];
            cc += sbe[d] * sWp[d * NF + t];
        }
        cst[128 + t] = uu;            // u[f]
        cst[136 + t] = cc + sbp[t];   // c8[f]
    }
}

// ---- prep: X16=fp16(x), Y16=fp16(x@G), proj=x@M+c8, r[b]=sum_s x.u, term1 ----
__global__ __launch_bounds__(256) void prep_kernel(
    const float* __restrict__ x, const float* __restrict__ cst,
    _Float16* __restrict__ X16, _Float16* __restrict__ Y16,
    float* __restrict__ proj, float* __restrict__ r, double* __restrict__ acc)
{
    __shared__ float sG[64], sM[64], su[8], sc[8];
    __shared__ float red[4];
    const int t = threadIdx.x, lane = t & 63, w = t >> 6;
    if (t < 64) sG[t] = cst[t];
    else if (t < 128) sM[t - 64] = cst[t];
    else if (t < 136) su[t - 128] = cst[t];
    else if (t < 144) sc[t - 136] = cst[t];
    __syncthreads();
    const int b = blockIdx.x * 4 + w;
    const size_t base = (size_t)b * KL + lane * 8;
    const f32x4 x0 = *(const f32x4*)&x[base];
    const f32x4 x1 = *(const f32x4*)&x[base + 4];
    float xv[8] = {x0[0], x0[1], x0[2], x0[3], x1[0], x1[1], x1[2], x1[3]};
    float yv[8], pv[8];
    #pragma unroll
    for (int f2 = 0; f2 < 8; ++f2) { yv[f2] = 0.f; pv[f2] = sc[f2]; }
    #pragma unroll
    for (int f = 0; f < 8; ++f)
        #pragma unroll
        for (int f2 = 0; f2 < 8; ++f2) {
            yv[f2] += xv[f] * sG[f * 8 + f2];
            pv[f2] += xv[f] * sM[f * 8 + f2];
        }
    half8 hx, hy;
    #pragma unroll
    for (int j = 0; j < 8; ++j) { hx[j] = (_Float16)xv[j]; hy[j] = (_Float16)yv[j]; }
    *(half8*)&X16[base] = hx;
    *(half8*)&Y16[base] = hy;
    *(f32x4*)&proj[base] = (f32x4){pv[0], pv[1], pv[2], pv[3]};
    *(f32x4*)&proj[base + 4] = (f32x4){pv[4], pv[5], pv[6], pv[7]};
    // r[b] = sum_s x[b,s].u  (proven shfl_down reduce; result in lane 0)
    float rv = 0.f;
    #pragma unroll
    for (int f = 0; f < 8; ++f) rv += xv[f] * su[f];
    #pragma unroll
    for (int o = 32; o > 0; o >>= 1) rv += __shfl_down(rv, o, 64);
    if (lane == 0) r[b] = rv;
    float s1 = 0.f;
    #pragma unroll
    for (int j = 0; j < 8; ++j) { const float d = pv[j] - xv[j]; s1 += d * d; }
    const float tot = blk_reduce(s1, red);
    if (t == 0) atomicAdd(&acc[(size_t)(blockIdx.x & 31) * 8], (double)tot);
}

// ---- dot = X @ Y^T (K=512) fp16 MFMA, lower-tri, 3-buf depth-2 pipeline ----
// epilogue adds column term: C[i][j] = dot + r[j]  (mirror: C[j][i] = dot + r[i])
__global__ __launch_bounds__(256) void attn_gemm_kernel(
    const _Float16* __restrict__ Xf, const _Float16* __restrict__ Yf,
    const float* __restrict__ rvec, float* __restrict__ C)
{
    __shared__ __align__(16) char smem_raw[49152];
    _Float16* smem = (_Float16*)smem_raw;

    const int t = threadIdx.x;
    const int lane = t & 63, wid = t >> 6;
    const int wr = wid >> 1, wc = wid & 1;

    const int bid0 = blockIdx.x;
    const int bid = (bid0 & 7) * 66 + (bid0 >> 3);

    int it = (int)((sqrtf(8.0f * (float)bid + 1.0f) - 1.0f) * 0.5f);
    while ((it + 1) * (it + 2) / 2 <= bid) ++it;
    while (it * (it + 1) / 2 > bid) --it;
    const int jt = bid - it * (it + 1) / 2;
    const int i0 = it * 128, j0 = jt * 128;

    f32x4 acc[4][4];
    #pragma unroll
    for (int m = 0; m < 4; ++m)
        #pragma unroll
        for (int n = 0; n < 4; ++n) acc[m][n] = (f32x4){0.f, 0.f, 0.f, 0.f};

    const int lrow = lane & 15, g = lane >> 4;
    const int ksw = (g ^ ((lrow >> 1) & 3)) * 8;

    const int c0 = t, c1 = t + 256;
    const int r0 = c0 >> 2, r1 = c1 >> 2;
    const int cs0 = ((c0 & 3) ^ ((r0 >> 1) & 3)) * 8;
    const int cs1 = ((c1 & 3) ^ ((r1 >> 1) & 3)) * 8;
    const _Float16* pa0 = Xf + (size_t)(i0 + r0) * KL + cs0;
    const _Float16* pa1 = Xf + (size_t)(i0 + r1) * KL + cs1;
    const _Float16* pb0 = Yf + (size_t)(j0 + r0) * KL + cs0;
    const _Float16* pb1 = Yf + (size_t)(j0 + r1) * KL + cs1;
    _Float16* d0 = smem + c0 * 8;
    _Float16* d1 = smem + c1 * 8;

#define STG(BUF, KH) { \
    GLD16(pa0 + (KH), d0 + (BUF) * 8192); \
    GLD16(pa1 + (KH), d1 + (BUF) * 8192); \
    GLD16(pb0 + (KH), d0 + (BUF) * 8192 + 4096); \
    GLD16(pb1 + (KH), d1 + (BUF) * 8192 + 4096); }

    const int roA = wr * 2048 + lrow * 32 + ksw;
    const int roB = wc * 2048 + lrow * 32 + ksw;

#define COMPUTE(BUF) { \
    const _Float16* sA = smem + (BUF) * 8192; \
    const _Float16* sB = sA + 4096; \
    half8 fa[4], fb[4]; \
    _Pragma("unroll") \
    for (int m = 0; m < 4; ++m) { \
        fa[m] = *(const half8*)&sA[roA + m * 512]; \
        fb[m] = *(const half8*)&sB[roB + m * 512]; \
    } \
    __builtin_amdgcn_s_setprio(1); \
    _Pragma("unroll") \
    for (int m = 0; m < 4; ++m) \
        _Pragma("unroll") \
        for (int n = 0; n < 4; ++n) \
            acc[m][n] = __builtin_amdgcn_mfma_f32_16x16x32_f16(fa[m], fb[n], acc[m][n], 0, 0, 0); \
    __builtin_amdgcn_s_setprio(0); }

    STG(0, 0); STG(1, 32);
    pa0 += 64; pa1 += 64; pb0 += 64; pb1 += 64;
    #pragma unroll 1
    for (int io = 0; io < 4; ++io) {
        WAITVM(4); __builtin_amdgcn_s_barrier(); STG(2, 0);  COMPUTE(0);
        WAITVM(4); __builtin_amdgcn_s_barrier(); STG(0, 32); COMPUTE(1);
        WAITVM(4); __builtin_amdgcn_s_barrier(); STG(1, 64); COMPUTE(2);
        pa0 += 96; pa1 += 96; pb0 += 96; pb1 += 96;
    }
    WAITVM(4); __builtin_amdgcn_s_barrier(); STG(2, 0);  COMPUTE(0);
    WAITVM(4); __builtin_amdgcn_s_barrier(); STG(0, 32); COMPUTE(1);
    WAITVM(4); __builtin_amdgcn_s_barrier(); COMPUTE(2);
    WAITVM(0); __builtin_amdgcn_s_barrier(); COMPUTE(0);
#undef STG
#undef COMPUTE

    // column-term r[j] for the direct store (depends on n only)
    float rj[4];
    #pragma unroll
    for (int n = 0; n < 4; ++n) rj[n] = rvec[j0 + wc * 64 + n * 16 + lrow];

    const int diag = (it == jt);
    #pragma unroll
    for (int m = 0; m < 4; ++m)
        #pragma unroll
        for (int n = 0; n < 4; ++n)
            #pragma unroll
            for (int rr = 0; rr < 4; ++rr) {
                const int i = i0 + wr * 64 + m * 16 + g * 4 + rr;
                const int j = j0 + wc * 64 + n * 16 + lrow;
                C[(size_t)i * NB + j] = acc[m][n][rr] + rj[n];
            }

    if (!diag) {
        float* fsm = (float*)smem_raw;
        #pragma unroll
        for (int p = 0; p < 2; ++p) {
            __syncthreads();
            if (wc == p) {
                #pragma unroll
                for (int m = 0; m < 4; ++m)
                    #pragma unroll
                    for (int n = 0; n < 4; ++n) {
                        const int jl = n * 16 + lrow;
                        const int ilocb = wr * 64 + m * 16 + g * 4;
                        *(f32x4*)&fsm[jl * 128 + (ilocb ^ ((jl & 7) << 2))] = acc[m][n];
                    }
            }
            __syncthreads();
            #pragma unroll
            for (int rep = 0; rep < 8; ++rep) {
                const int idx = rep * 256 + t;
                const int jl = idx >> 5, ic4 = (idx & 31) * 4;
                f32x4 v = *(const f32x4*)&fsm[jl * 128 + (ic4 ^ ((jl & 7) << 2))];
                const f32x4 rv4 = *(const f32x4*)&rvec[i0 + ic4];   // row term r[i]
                v[0] += rv4[0]; v[1] += rv4[1]; v[2] += rv4[2]; v[3] += rv4[3];
                *(f32x4*)&C[(size_t)(j0 + p * 64 + jl) * NB + i0 + ic4] = v;
            }
        }
    }
}

// ---------------- fused top-k + gathered diffs: one wave per row ----------------
__global__ __launch_bounds__(256) void topk_diffs_kernel(
    const float* __restrict__ attn, const float* __restrict__ proj, double* __restrict__ acc)
{
    __shared__ __align__(16) float rows[4][NB];   // 64 KB
    __shared__ int sidx[4][NK];
    const int t = threadIdx.x, lane = t & 63, w = t >> 6;
    const int b = blockIdx.x * 4 + w;
    float* srow = rows[w];

    // row -> LDS via global_load_lds (wave-uniform dst base, lane x 16B; no barrier needed)
    const float* rowsrc = attn + (size_t)b * NB;
    #pragma unroll
    for (int j = 0; j < 16; ++j)
        GLD16(rowsrc + j * 256 + lane * 4, srow + j * 256);
    WAITVM(0);
    if (lane == (b & 63)) srow[b] = -INFINITY;   // mask self (owner lane)

#define SCAN_CHUNK(Q, CV, CI) { \
    CV = -INFINITY; CI = 0; \
    _Pragma("unroll") \
    for (int j = 0; j < 16; ++j) { \
        const int e = ((Q) * 16 + j) * 64 + lane; \
        const float v = srow[e]; \
        if (v > CV) { CV = v; CI = e; } \
    } }

    float cv0, cv1, cv2, cv3; int ci0, ci1, ci2, ci3;
    SCAN_CHUNK(0, cv0, ci0); SCAN_CHUNK(1, cv1, ci1);
    SCAN_CHUNK(2, cv2, ci2); SCAN_CHUNK(3, cv3, ci3);

    for (int k = 0; k < NK; ++k) {
        float bv = cv0; int bi = ci0;
        if (cv1 > bv || (cv1 == bv && ci1 < bi)) { bv = cv1; bi = ci1; }
        if (cv2 > bv || (cv2 == bv && ci2 < bi)) { bv = cv2; bi = ci2; }
        if (cv3 > bv || (cv3 == bv && ci3 < bi)) { bv = cv3; bi = ci3; }
        // proven (value,index) shfl_xor butterfly; exact lowest-index tie-break
        float v = bv; int idx = bi;
        #pragma unroll
        for (int o = 32; o > 0; o >>= 1) {
            const float v2 = __shfl_xor(v, o, 64);
            const int  i2 = __shfl_xor(idx, o, 64);
            if (v2 > v || (v2 == v && i2 < idx)) { v = v2; idx = i2; }
        }
        if (lane == 0) sidx[w][k] = idx;
        if ((idx & 63) == lane) {                 // owner invalidates + rescans its chunk
            srow[idx] = -INFINITY;
            switch (idx >> 10) {                  // wave-uniform
                case 0: SCAN_CHUNK(0, cv0, ci0); break;
                case 1: SCAN_CHUNK(1, cv1, ci1); break;
                case 2: SCAN_CHUNK(2, cv2, ci2); break;
                default: SCAN_CHUNK(3, cv3, ci3); break;
            }
        }
    }
#undef SCAN_CHUNK

    // diffs: lane holds elems [lane*8, lane*8+8); S-diff loads the NEXT 8 directly
    float s1 = 0.f, s2 = 0.f;
    float prev[8];
    for (int k = 0; k < NK; ++k) {
        const float* pp = proj + (size_t)sidx[w][k] * 512 + lane * 8;
        const f32x4 a0 = *(const f32x4*)pp;
        const f32x4 a1 = *(const f32x4*)(pp + 4);
        float cur[8] = {a0[0], a0[1], a0[2], a0[3], a1[0], a1[1], a1[2], a1[3]};
        if (k) {
            #pragma unroll
            for (int j = 0; j < 8; ++j) { const float d = cur[j] - prev[j]; s1 += d * d; }
        }
        if (lane < 63) {
            const f32x4 n0 = *(const f32x4*)(pp + 8);
            const f32x4 n1 = *(const f32x4*)(pp + 12);
            const float nxt[8] = {n0[0], n0[1], n0[2], n0[3], n1[0], n1[1], n1[2], n1[3]};
            #pragma unroll
            for (int j = 0; j < 8; ++j) { const float d = nxt[j] - cur[j]; s2 += d * d; }
        }
        #pragma unroll
        for (int j = 0; j < 8; ++j) prev[j] = cur[j];
    }
    #pragma unroll
    for (int o = 32; o > 0; o >>= 1) { s1 += __shfl_down(s1, o, 64); s2 += __shfl_down(s2, o, 64); }
    if (lane == 0) {
        const size_t slot = (size_t)(blockIdx.x & 31) * 8;
        atomicAdd(&acc[(size_t)32 * 8 + slot], (double)s1);
        atomicAdd(&acc[(size_t)64 * 8 + slot], (double)s2);
    }
}

// ---------------- finalize loss ----------------
__global__ void finalize_kernel(const double* __restrict__ acc, float* __restrict__ out) {
    if (threadIdx.x == 0) {
        double s0 = 0.0, s1 = 0.0, s2 = 0.0;
        #pragma unroll
        for (int i = 0; i < 32; ++i) {
            s0 += acc[(size_t)i * 8];
            s1 += acc[(size_t)(32 + i) * 8];
            s2 += acc[(size_t)(64 + i) * 8];
        }
        out[0] = (float)(s0 / 2097152.0 + s1 / 31457280.0 + s2 / 33030144.0);
    }
}

extern "C" void kernel_launch(void* const* d_in, const int* in_sizes, int n_in,
                              void* d_out, int out_size, void* d_ws, size_t ws_size,
                              hipStream_t stream) {
    const float* x    = (const float*)d_in[0];
    const float* Wemb = (const float*)d_in[1];
    const float* bemb = (const float*)d_in[2];
    const float* Wp   = (const float*)d_in[3];
    const float* bp   = (const float*)d_in[4];
    float* out  = (float*)d_out;
    float* proj = out + 1;                       // x_rec_proj, B*S*F floats

    char* ws = (char*)d_ws;
    _Float16* X16 = (_Float16*)ws;                               // 4 MB
    _Float16* Y16 = (_Float16*)(ws + ((size_t)4 << 20));         // 4 MB
    float*  attn  = (float*)(ws + ((size_t)8 << 20));            // 64 MB
    float*  cst   = (float*)(ws + ((size_t)72 << 20));           // 256 floats
    float*  rvec  = (float*)(ws + ((size_t)72 << 20) + 4096);    // 16 KB
    double* acc   = (double*)(ws + ((size_t)72 << 20) + 65536);  // 96 slots x 64B

    hipMemsetAsync(acc, 0, 96 * 8 * sizeof(double), stream);
    consts_kernel<<<1, 64, 0, stream>>>(Wemb, bemb, Wp, bp, cst);
    prep_kernel<<<NB / 4, 256, 0, stream>>>(x, cst, X16, Y16, proj, rvec, acc);
    attn_gemm_kernel<<<(32 * 33) / 2, 256, 0, stream>>>(X16, Y16, rvec, attn);
    topk_diffs_kernel<<<NB / 4, 256, 0, stream>>>(attn, proj, acc);
    finalize_kernel<<<1, 64, 0, stream>>>(acc, out);
}

// Round 12
// 98.072 us; speedup vs baseline: 1.1723x; 1.1723x over previous
//
#include <hip/hip_runtime.h>
#include <math.h>

#define NB 4096   // batch
#define NS 64     // seq
#define NF 8      // feat
#define ND 64     // d_model
#define KL 512    // GEMM K = NS*NF (rank-8 trick)
#define NK 16     // top-k

typedef _Float16 half8 __attribute__((ext_vector_type(8)));
typedef float    f32x4 __attribute__((ext_vector_type(4)));

#define GLD16(src, dst) \
  __builtin_amdgcn_global_load_lds((const __attribute__((address_space(1))) void*)(src), \
                                   (__attribute__((address_space(3))) void*)(dst), 16, 0, 0)

#define WAITVM(N) asm volatile("s_waitcnt vmcnt(" #N ")" ::: "memory")

// ---------------- block reduce helper ----------------
__device__ __forceinline__ float blk_reduce(float v, float* red) {
    #pragma unroll
    for (int o = 32; o > 0; o >>= 1) v += __shfl_down(v, o, 64);
    const int t = threadIdx.x;
    __syncthreads();
    if ((t & 63) == 0) red[t >> 6] = v;
    __syncthreads();
    float r = 0.f;
    if (t == 0) r = red[0] + red[1] + red[2] + red[3];
    return r;
}

// ---- consts: G = We@We^T [8x8], M = We@Wp [8x8], u = We@be [8], c8 = be@Wp + bp [8] ----
__global__ __launch_bounds__(64) void consts_kernel(
    const float* __restrict__ Wemb, const float* __restrict__ bemb,
    const float* __restrict__ Wp, const float* __restrict__ bp, float* __restrict__ cst)
{
    __shared__ float sWe[NF * ND];   // [f][d]
    __shared__ float sWp[ND * NF];   // [d][f]
    __shared__ float sbe[ND];
    __shared__ float sbp[NF];
    const int t = threadIdx.x;
    #pragma unroll
    for (int i = 0; i < 8; ++i) { sWe[t + i * 64] = Wemb[t + i * 64]; sWp[t + i * 64] = Wp[t + i * 64]; }
    sbe[t] = bemb[t];
    if (t < NF) sbp[t] = bp[t];
    __syncthreads();
    const int f = t >> 3, f2 = t & 7;
    float g = 0.f, m = 0.f;
    #pragma unroll
    for (int d = 0; d < ND; ++d) {
        g += sWe[f * ND + d] * sWe[f2 * ND + d];
        m += sWe[f * ND + d] * sWp[d * NF + f2];
    }
    cst[t] = g;          // G[f][f2]
    cst[64 + t] = m;     // M[f][f2]
    if (t < NF) {
        float uu = 0.f, cc = 0.f;
        #pragma unroll
        for (int d = 0; d < ND; ++d) {
            uu += sWe[t * ND + d] * sbe[d];
            cc += sbe[d] * sWp[d * NF + t];
        }
        cst[128 + t] = uu;            // u[f]
        cst[136 + t] = cc + sbp[t];   // c8[f]
    }
}

// ---- prep: X16=fp16(x), Y16=fp16(x@G), proj=x@M+c8, r[b]=sum_s x.u, term1 ----
__global__ __launch_bounds__(256) void prep_kernel(
    const float* __restrict__ x, const float* __restrict__ cst,
    _Float16* __restrict__ X16, _Float16* __restrict__ Y16,
    float* __restrict__ proj, float* __restrict__ r, double* __restrict__ acc)
{
    __shared__ float sG[64], sM[64], su[8], sc[8];
    __shared__ float red[4];
    const int t = threadIdx.x, lane = t & 63, w = t >> 6;
    if (t < 64) sG[t] = cst[t];
    else if (t < 128) sM[t - 64] = cst[t];
    else if (t < 136) su[t - 128] = cst[t];
    else if (t < 144) sc[t - 136] = cst[t];
    __syncthreads();
    const int b = blockIdx.x * 4 + w;
    const size_t base = (size_t)b * KL + lane * 8;
    const f32x4 x0 = *(const f32x4*)&x[base];
    const f32x4 x1 = *(const f32x4*)&x[base + 4];
    float xv[8] = {x0[0], x0[1], x0[2], x0[3], x1[0], x1[1], x1[2], x1[3]};
    float yv[8], pv[8];
    #pragma unroll
    for (int f2 = 0; f2 < 8; ++f2) { yv[f2] = 0.f; pv[f2] = sc[f2]; }
    #pragma unroll
    for (int f = 0; f < 8; ++f)
        #pragma unroll
        for (int f2 = 0; f2 < 8; ++f2) {
            yv[f2] += xv[f] * sG[f * 8 + f2];
            pv[f2] += xv[f] * sM[f * 8 + f2];
        }
    half8 hx, hy;
    #pragma unroll
    for (int j = 0; j < 8; ++j) { hx[j] = (_Float16)xv[j]; hy[j] = (_Float16)yv[j]; }
    *(half8*)&X16[base] = hx;
    *(half8*)&Y16[base] = hy;
    *(f32x4*)&proj[base] = (f32x4){pv[0], pv[1], pv[2], pv[3]};
    *(f32x4*)&proj[base + 4] = (f32x4){pv[4], pv[5], pv[6], pv[7]};
    float rv = 0.f;
    #pragma unroll
    for (int f = 0; f < 8; ++f) rv += xv[f] * su[f];
    #pragma unroll
    for (int o = 32; o > 0; o >>= 1) rv += __shfl_down(rv, o, 64);
    if (lane == 0) r[b] = rv;
    float s1 = 0.f;
    #pragma unroll
    for (int j = 0; j < 8; ++j) { const float d = pv[j] - xv[j]; s1 += d * d; }
    const float tot = blk_reduce(s1, red);
    if (t == 0) atomicAdd(&acc[(size_t)(blockIdx.x & 31) * 8], (double)tot);
}

// ---- dot = X @ Y^T (K=512) fp16 MFMA, lower-tri, 3-buf depth-2 pipeline ----
// epilogue adds column term: C[i][j] = dot + r[j]  (mirror: C[j][i] = dot + r[i])
__global__ __launch_bounds__(256) void attn_gemm_kernel(
    const _Float16* __restrict__ Xf, const _Float16* __restrict__ Yf,
    const float* __restrict__ rvec, float* __restrict__ C)
{
    __shared__ __align__(16) char smem_raw[49152];
    _Float16* smem = (_Float16*)smem_raw;

    const int t = threadIdx.x;
    const int lane = t & 63, wid = t >> 6;
    const int wr = wid >> 1, wc = wid & 1;

    const int bid0 = blockIdx.x;
    const int bid = (bid0 & 7) * 66 + (bid0 >> 3);

    int it = (int)((sqrtf(8.0f * (float)bid + 1.0f) - 1.0f) * 0.5f);
    while ((it + 1) * (it + 2) / 2 <= bid) ++it;
    while (it * (it + 1) / 2 > bid) --it;
    const int jt = bid - it * (it + 1) / 2;
    const int i0 = it * 128, j0 = jt * 128;

    f32x4 acc[4][4];
    #pragma unroll
    for (int m = 0; m < 4; ++m)
        #pragma unroll
        for (int n = 0; n < 4; ++n) acc[m][n] = (f32x4){0.f, 0.f, 0.f, 0.f};

    const int lrow = lane & 15, g = lane >> 4;
    const int ksw = (g ^ ((lrow >> 1) & 3)) * 8;

    const int c0 = t, c1 = t + 256;
    const int r0 = c0 >> 2, r1 = c1 >> 2;
    const int cs0 = ((c0 & 3) ^ ((r0 >> 1) & 3)) * 8;
    const int cs1 = ((c1 & 3) ^ ((r1 >> 1) & 3)) * 8;
    const _Float16* pa0 = Xf + (size_t)(i0 + r0) * KL + cs0;
    const _Float16* pa1 = Xf + (size_t)(i0 + r1) * KL + cs1;
    const _Float16* pb0 = Yf + (size_t)(j0 + r0) * KL + cs0;
    const _Float16* pb1 = Yf + (size_t)(j0 + r1) * KL + cs1;
    _Float16* d0 = smem + c0 * 8;
    _Float16* d1 = smem + c1 * 8;

#define STG(BUF, KH) { \
    GLD16(pa0 + (KH), d0 + (BUF) * 8192); \
    GLD16(pa1 + (KH), d1 + (BUF) * 8192); \
    GLD16(pb0 + (KH), d0 + (BUF) * 8192 + 4096); \
    GLD16(pb1 + (KH), d1 + (BUF) * 8192 + 4096); }

    const int roA = wr * 2048 + lrow * 32 + ksw;
    const int roB = wc * 2048 + lrow * 32 + ksw;

#define COMPUTE(BUF) { \
    const _Float16* sA = smem + (BUF) * 8192; \
    const _Float16* sB = sA + 4096; \
    half8 fa[4], fb[4]; \
    _Pragma("unroll") \
    for (int m = 0; m < 4; ++m) { \
        fa[m] = *(const half8*)&sA[roA + m * 512]; \
        fb[m] = *(const half8*)&sB[roB + m * 512]; \
    } \
    __builtin_amdgcn_s_setprio(1); \
    _Pragma("unroll") \
    for (int m = 0; m < 4; ++m) \
        _Pragma("unroll") \
        for (int n = 0; n < 4; ++n) \
            acc[m][n] = __builtin_amdgcn_mfma_f32_16x16x32_f16(fa[m], fb[n], acc[m][n], 0, 0, 0); \
    __builtin_amdgcn_s_setprio(0); }

    STG(0, 0); STG(1, 32);
    pa0 += 64; pa1 += 64; pb0 += 64; pb1 += 64;
    #pragma unroll 1
    for (int io = 0; io < 4; ++io) {
        WAITVM(4); __builtin_amdgcn_s_barrier(); STG(2, 0);  COMPUTE(0);
        WAITVM(4); __builtin_amdgcn_s_barrier(); STG(0, 32); COMPUTE(1);
        WAITVM(4); __builtin_amdgcn_s_barrier(); STG(1, 64); COMPUTE(2);
        pa0 += 96; pa1 += 96; pb0 += 96; pb1 += 96;
    }
    WAITVM(4); __builtin_amdgcn_s_barrier(); STG(2, 0);  COMPUTE(0);
    WAITVM(4); __builtin_amdgcn_s_barrier(); STG(0, 32); COMPUTE(1);
    WAITVM(4); __builtin_amdgcn_s_barrier(); COMPUTE(2);
    WAITVM(0); __builtin_amdgcn_s_barrier(); COMPUTE(0);
#undef STG
#undef COMPUTE

    // column-term r[j] for the direct store (depends on n only)
    float rj[4];
    #pragma unroll
    for (int n = 0; n < 4; ++n) rj[n] = rvec[j0 + wc * 64 + n * 16 + lrow];

    const int diag = (it == jt);
    #pragma unroll
    for (int m = 0; m < 4; ++m)
        #pragma unroll
        for (int n = 0; n < 4; ++n)
            #pragma unroll
            for (int rr = 0; rr < 4; ++rr) {
                const int i = i0 + wr * 64 + m * 16 + g * 4 + rr;
                const int j = j0 + wc * 64 + n * 16 + lrow;
                C[(size_t)i * NB + j] = acc[m][n][rr] + rj[n];
            }

    if (!diag) {
        float* fsm = (float*)smem_raw;
        #pragma unroll
        for (int p = 0; p < 2; ++p) {
            __syncthreads();
            if (wc == p) {
                #pragma unroll
                for (int m = 0; m < 4; ++m)
                    #pragma unroll
                    for (int n = 0; n < 4; ++n) {
                        const int jl = n * 16 + lrow;
                        const int ilocb = wr * 64 + m * 16 + g * 4;
                        *(f32x4*)&fsm[jl * 128 + (ilocb ^ ((jl & 7) << 2))] = acc[m][n];
                    }
            }
            __syncthreads();
            #pragma unroll
            for (int rep = 0; rep < 8; ++rep) {
                const int idx = rep * 256 + t;
                const int jl = idx >> 5, ic4 = (idx & 31) * 4;
                f32x4 v = *(const f32x4*)&fsm[jl * 128 + (ic4 ^ ((jl & 7) << 2))];
                const f32x4 rv4 = *(const f32x4*)&rvec[i0 + ic4];   // row term r[i]
                v[0] += rv4[0]; v[1] += rv4[1]; v[2] += rv4[2]; v[3] += rv4[3];
                *(f32x4*)&C[(size_t)(j0 + p * 64 + jl) * NB + i0 + ic4] = v;
            }
        }
    }
}

// ---- fused top-k + gathered diffs: one wave per row, REGISTER-resident, no LDS ----
// row kept as sortable u32 in 64 regs/lane (lane owns contiguous [lane*64, lane*64+64));
// per extraction: 6-shfl value butterfly + ballot + 1 shfl for index (exact min-index ties)
__global__ __launch_bounds__(256) void topk_diffs_kernel(
    const float* __restrict__ attn, const float* __restrict__ proj, double* __restrict__ acc)
{
    const int t = threadIdx.x, lane = t & 63, w = t >> 6;
    const int b = blockIdx.x * 4 + w;
    const float* rowsrc = attn + (size_t)b * NB;

    // load + convert to sortable uint (monotone); mask self element to 0 (= -inf)
    unsigned rr[64];
    #pragma unroll
    for (int j = 0; j < 16; ++j) {
        const uint4 v = *(const uint4*)(rowsrc + lane * 64 + j * 4);
        #pragma unroll
        for (int c = 0; c < 4; ++c) {
            const unsigned u = ((const unsigned*)&v)[c];
            const unsigned s = (u & 0x80000000u) ? ~u : (u | 0x80000000u);
            const int e = lane * 64 + j * 4 + c;
            rr[j * 4 + c] = (e == b) ? 0u : s;
        }
    }

    // per-lane chunk caches (4 x 16 contiguous elems); strict > keeps lowest index
#define BUILD(Q, CV, LI) { \
    CV = 0u; LI = (Q) * 16; \
    _Pragma("unroll") \
    for (int j2 = 0; j2 < 16; ++j2) { \
        const unsigned v2 = rr[(Q) * 16 + j2]; \
        if (v2 > CV) { CV = v2; LI = (Q) * 16 + j2; } \
    } }

    unsigned cv0, cv1, cv2, cv3; int li0, li1, li2, li3;
    BUILD(0, cv0, li0) BUILD(1, cv1, li1) BUILD(2, cv2, li2) BUILD(3, cv3, li3)

    float s1 = 0.f, s2 = 0.f;
    float prev[8];

    for (int k = 0; k < NK; ++k) {
        // lane candidate (ascending q, strict > keeps lowest local index)
        unsigned bv = cv0; int li = li0;
        if (cv1 > bv) { bv = cv1; li = li1; }
        if (cv2 > bv) { bv = cv2; li = li2; }
        if (cv3 > bv) { bv = cv3; li = li3; }
        // value-only butterfly max (6 shfls), then ballot for exact winner
        unsigned m = bv;
        #pragma unroll
        for (int o = 1; o <= 32; o <<= 1)
            m = max(m, (unsigned)__shfl_xor((int)m, o, 64));
        const unsigned long long mask = __ballot(bv == m);
        const int wl = (int)(__ffsll((long long)mask) - 1);   // lowest lane = lowest index
        const int gi = lane * 64 + li;
        const int idx = __shfl(gi, wl, 64);                   // wave-uniform

        // gather proj row idx now (loads overlap the rescan + next butterfly)
        const float* pp = proj + (size_t)idx * 512 + lane * 8;
        const f32x4 a0 = *(const f32x4*)pp;
        const f32x4 a1 = *(const f32x4*)(pp + 4);
        float cur[8] = {a0[0], a0[1], a0[2], a0[3], a1[0], a1[1], a1[2], a1[3]};
        if (k) {
            #pragma unroll
            for (int j = 0; j < 8; ++j) { const float d = cur[j] - prev[j]; s1 += d * d; }
        }
        if (lane < 63) {
            const f32x4 n0 = *(const f32x4*)(pp + 8);
            const f32x4 n1 = *(const f32x4*)(pp + 12);
            const float nxt[8] = {n0[0], n0[1], n0[2], n0[3], n1[0], n1[1], n1[2], n1[3]};
            #pragma unroll
            for (int j = 0; j < 8; ++j) { const float d = nxt[j] - cur[j]; s2 += d * d; }
        }
        #pragma unroll
        for (int j = 0; j < 8; ++j) prev[j] = cur[j];

        // invalidate + rescan: uniform control flow; only owner lane's element matches
#define INVSCAN(Q, CV, LI) { \
    _Pragma("unroll") \
    for (int j2 = 0; j2 < 16; ++j2) \
        if (lane * 64 + (Q) * 16 + j2 == idx) rr[(Q) * 16 + j2] = 0u; \
    BUILD(Q, CV, LI) }

        switch ((idx >> 4) & 3) {                 // wave-uniform chunk select
            case 0: INVSCAN(0, cv0, li0) break;
            case 1: INVSCAN(1, cv1, li1) break;
            case 2: INVSCAN(2, cv2, li2) break;
            default: INVSCAN(3, cv3, li3) break;
        }
#undef INVSCAN
    }
#undef BUILD

    #pragma unroll
    for (int o = 32; o > 0; o >>= 1) { s1 += __shfl_down(s1, o, 64); s2 += __shfl_down(s2, o, 64); }
    if (lane == 0) {
        const size_t slot = (size_t)(blockIdx.x & 31) * 8;
        atomicAdd(&acc[(size_t)32 * 8 + slot], (double)s1);
        atomicAdd(&acc[(size_t)64 * 8 + slot], (double)s2);
    }
}

// ---------------- finalize loss ----------------
__global__ void finalize_kernel(const double* __restrict__ acc, float* __restrict__ out) {
    if (threadIdx.x == 0) {
        double s0 = 0.0, s1 = 0.0, s2 = 0.0;
        #pragma unroll
        for (int i = 0; i < 32; ++i) {
            s0 += acc[(size_t)i * 8];
            s1 += acc[(size_t)(32 + i) * 8];
            s2 += acc[(size_t)(64 + i) * 8];
        }
        out[0] = (float)(s0 / 2097152.0 + s1 / 31457280.0 + s2 / 33030144.0);
    }
}

extern "C" void kernel_launch(void* const* d_in, const int* in_sizes, int n_in,
                              void* d_out, int out_size, void* d_ws, size_t ws_size,
                              hipStream_t stream) {
    const float* x    = (const float*)d_in[0];
    const float* Wemb = (const float*)d_in[1];
    const float* bemb = (const float*)d_in[2];
    const float* Wp   = (const float*)d_in[3];
    const float* bp   = (const float*)d_in[4];
    float* out  = (float*)d_out;
    float* proj = out + 1;                       // x_rec_proj, B*S*F floats

    char* ws = (char*)d_ws;
    _Float16* X16 = (_Float16*)ws;                               // 4 MB
    _Float16* Y16 = (_Float16*)(ws + ((size_t)4 << 20));         // 4 MB
    float*  attn  = (float*)(ws + ((size_t)8 << 20));            // 64 MB
    float*  cst   = (float*)(ws + ((size_t)72 << 20));           // 256 floats
    float*  rvec  = (float*)(ws + ((size_t)72 << 20) + 4096);    // 16 KB
    double* acc   = (double*)(ws + ((size_t)72 << 20) + 65536);  // 96 slots x 64B

    hipMemsetAsync(acc, 0, 96 * 8 * sizeof(double), stream);
    consts_kernel<<<1, 64, 0, stream>>>(Wemb, bemb, Wp, bp, cst);
    prep_kernel<<<NB / 4, 256, 0, stream>>>(x, cst, X16, Y16, proj, rvec, acc);
    attn_gemm_kernel<<<(32 * 33) / 2, 256, 0, stream>>>(X16, Y16, rvec, attn);
    topk_diffs_kernel<<<NB / 4, 256, 0, stream>>>(attn, proj, acc);
    finalize_kernel<<<1, 64, 0, stream>>>(acc, out);
}

// Round 13
// 79.147 us; speedup vs baseline: 1.4526x; 1.2391x over previous
//
#include <hip/hip_runtime.h>
#include <math.h>

#define NB 4096   // batch
#define NS 64     // seq
#define NF 8      // feat
#define ND 64     // d_model
#define KL 512    // GEMM K = NS*NF (rank-8 trick)
#define NK 16     // top-k

typedef _Float16 half8 __attribute__((ext_vector_type(8)));
typedef float    f32x4 __attribute__((ext_vector_type(4)));
typedef unsigned short u16x4 __attribute__((ext_vector_type(4)));

#define GLD16(src, dst) \
  __builtin_amdgcn_global_load_lds((const __attribute__((address_space(1))) void*)(src), \
                                   (__attribute__((address_space(3))) void*)(dst), 16, 0, 0)

#define WAITVM(N) asm volatile("s_waitcnt vmcnt(" #N ")" ::: "memory")

__device__ __forceinline__ unsigned short f2bf_rne(float f) {
    unsigned v = __float_as_uint(f);
    return (unsigned short)((v + 0x7FFFu + ((v >> 16) & 1u)) >> 16);
}

// ---------------- block reduce helper ----------------
__device__ __forceinline__ float blk_reduce(float v, float* red) {
    #pragma unroll
    for (int o = 32; o > 0; o >>= 1) v += __shfl_down(v, o, 64);
    const int t = threadIdx.x;
    __syncthreads();
    if ((t & 63) == 0) red[t >> 6] = v;
    __syncthreads();
    float r = 0.f;
    if (t == 0) r = red[0] + red[1] + red[2] + red[3];
    return r;
}

// ---- consts: G = We@We^T [8x8], M = We@Wp [8x8], u = We@be [8], c8 = be@Wp + bp [8] ----
__global__ __launch_bounds__(64) void consts_kernel(
    const float* __restrict__ Wemb, const float* __restrict__ bemb,
    const float* __restrict__ Wp, const float* __restrict__ bp, float* __restrict__ cst)
{
    __shared__ float sWe[NF * ND];   // [f][d]
    __shared__ float sWp[ND * NF];   // [d][f]
    __shared__ float sbe[ND];
    __shared__ float sbp[NF];
    const int t = threadIdx.x;
    #pragma unroll
    for (int i = 0; i < 8; ++i) { sWe[t + i * 64] = Wemb[t + i * 64]; sWp[t + i * 64] = Wp[t + i * 64]; }
    sbe[t] = bemb[t];
    if (t < NF) sbp[t] = bp[t];
    __syncthreads();
    const int f = t >> 3, f2 = t & 7;
    float g = 0.f, m = 0.f;
    #pragma unroll
    for (int d = 0; d < ND; ++d) {
        g += sWe[f * ND + d] * sWe[f2 * ND + d];
        m += sWe[f * ND + d] * sWp[d * NF + f2];
    }
    cst[t] = g;          // G[f][f2]
    cst[64 + t] = m;     // M[f][f2]
    if (t < NF) {
        float uu = 0.f, cc = 0.f;
        #pragma unroll
        for (int d = 0; d < ND; ++d) {
            uu += sWe[t * ND + d] * sbe[d];
            cc += sbe[d] * sWp[d * NF + t];
        }
        cst[128 + t] = uu;            // u[f]
        cst[136 + t] = cc + sbp[t];   // c8[f]
    }
}

// ---- prep: X16=fp16(x), Y16=fp16(x@G), proj=x@M+c8, r[b]=sum_s x.u, term1 ----
__global__ __launch_bounds__(256) void prep_kernel(
    const float* __restrict__ x, const float* __restrict__ cst,
    _Float16* __restrict__ X16, _Float16* __restrict__ Y16,
    float* __restrict__ proj, float* __restrict__ r, double* __restrict__ acc)
{
    __shared__ float sG[64], sM[64], su[8], sc[8];
    __shared__ float red[4];
    const int t = threadIdx.x, lane = t & 63, w = t >> 6;
    if (t < 64) sG[t] = cst[t];
    else if (t < 128) sM[t - 64] = cst[t];
    else if (t < 136) su[t - 128] = cst[t];
    else if (t < 144) sc[t - 136] = cst[t];
    __syncthreads();
    const int b = blockIdx.x * 4 + w;
    const size_t base = (size_t)b * KL + lane * 8;
    const f32x4 x0 = *(const f32x4*)&x[base];
    const f32x4 x1 = *(const f32x4*)&x[base + 4];
    float xv[8] = {x0[0], x0[1], x0[2], x0[3], x1[0], x1[1], x1[2], x1[3]};
    float yv[8], pv[8];
    #pragma unroll
    for (int f2 = 0; f2 < 8; ++f2) { yv[f2] = 0.f; pv[f2] = sc[f2]; }
    #pragma unroll
    for (int f = 0; f < 8; ++f)
        #pragma unroll
        for (int f2 = 0; f2 < 8; ++f2) {
            yv[f2] += xv[f] * sG[f * 8 + f2];
            pv[f2] += xv[f] * sM[f * 8 + f2];
        }
    half8 hx, hy;
    #pragma unroll
    for (int j = 0; j < 8; ++j) { hx[j] = (_Float16)xv[j]; hy[j] = (_Float16)yv[j]; }
    *(half8*)&X16[base] = hx;
    *(half8*)&Y16[base] = hy;
    *(f32x4*)&proj[base] = (f32x4){pv[0], pv[1], pv[2], pv[3]};
    *(f32x4*)&proj[base + 4] = (f32x4){pv[4], pv[5], pv[6], pv[7]};
    float rv = 0.f;
    #pragma unroll
    for (int f = 0; f < 8; ++f) rv += xv[f] * su[f];
    #pragma unroll
    for (int o = 32; o > 0; o >>= 1) rv += __shfl_down(rv, o, 64);
    if (lane == 0) r[b] = rv;
    float s1 = 0.f;
    #pragma unroll
    for (int j = 0; j < 8; ++j) { const float d = pv[j] - xv[j]; s1 += d * d; }
    const float tot = blk_reduce(s1, red);
    if (t == 0) atomicAdd(&acc[(size_t)(blockIdx.x & 31) * 8], (double)tot);
}

// ---- dot = X @ Y^T (K=512) fp16 MFMA, lower-tri, 3-buf depth-2 pipeline ----
// epilogue: C_bf16[i][j] = bf16(dot + r[j]); mirror C_bf16[j][i] = bf16(dot + r[i])
__global__ __launch_bounds__(256) void attn_gemm_kernel(
    const _Float16* __restrict__ Xf, const _Float16* __restrict__ Yf,
    const float* __restrict__ rvec, unsigned short* __restrict__ C)
{
    __shared__ __align__(16) char smem_raw[49152];
    _Float16* smem = (_Float16*)smem_raw;

    const int t = threadIdx.x;
    const int lane = t & 63, wid = t >> 6;
    const int wr = wid >> 1, wc = wid & 1;

    const int bid0 = blockIdx.x;
    const int bid = (bid0 & 7) * 66 + (bid0 >> 3);

    int it = (int)((sqrtf(8.0f * (float)bid + 1.0f) - 1.0f) * 0.5f);
    while ((it + 1) * (it + 2) / 2 <= bid) ++it;
    while (it * (it + 1) / 2 > bid) --it;
    const int jt = bid - it * (it + 1) / 2;
    const int i0 = it * 128, j0 = jt * 128;

    f32x4 acc[4][4];
    #pragma unroll
    for (int m = 0; m < 4; ++m)
        #pragma unroll
        for (int n = 0; n < 4; ++n) acc[m][n] = (f32x4){0.f, 0.f, 0.f, 0.f};

    const int lrow = lane & 15, g = lane >> 4;
    const int ksw = (g ^ ((lrow >> 1) & 3)) * 8;

    const int c0 = t, c1 = t + 256;
    const int r0 = c0 >> 2, r1 = c1 >> 2;
    const int cs0 = ((c0 & 3) ^ ((r0 >> 1) & 3)) * 8;
    const int cs1 = ((c1 & 3) ^ ((r1 >> 1) & 3)) * 8;
    const _Float16* pa0 = Xf + (size_t)(i0 + r0) * KL + cs0;
    const _Float16* pa1 = Xf + (size_t)(i0 + r1) * KL + cs1;
    const _Float16* pb0 = Yf + (size_t)(j0 + r0) * KL + cs0;
    const _Float16* pb1 = Yf + (size_t)(j0 + r1) * KL + cs1;
    _Float16* d0 = smem + c0 * 8;
    _Float16* d1 = smem + c1 * 8;

#define STG(BUF, KH) { \
    GLD16(pa0 + (KH), d0 + (BUF) * 8192); \
    GLD16(pa1 + (KH), d1 + (BUF) * 8192); \
    GLD16(pb0 + (KH), d0 + (BUF) * 8192 + 4096); \
    GLD16(pb1 + (KH), d1 + (BUF) * 8192 + 4096); }

    const int roA = wr * 2048 + lrow * 32 + ksw;
    const int roB = wc * 2048 + lrow * 32 + ksw;

#define COMPUTE(BUF) { \
    const _Float16* sA = smem + (BUF) * 8192; \
    const _Float16* sB = sA + 4096; \
    half8 fa[4], fb[4]; \
    _Pragma("unroll") \
    for (int m = 0; m < 4; ++m) { \
        fa[m] = *(const half8*)&sA[roA + m * 512]; \
        fb[m] = *(const half8*)&sB[roB + m * 512]; \
    } \
    __builtin_amdgcn_s_setprio(1); \
    _Pragma("unroll") \
    for (int m = 0; m < 4; ++m) \
        _Pragma("unroll") \
        for (int n = 0; n < 4; ++n) \
            acc[m][n] = __builtin_amdgcn_mfma_f32_16x16x32_f16(fa[m], fb[n], acc[m][n], 0, 0, 0); \
    __builtin_amdgcn_s_setprio(0); }

    STG(0, 0); STG(1, 32);
    pa0 += 64; pa1 += 64; pb0 += 64; pb1 += 64;
    #pragma unroll 1
    for (int io = 0; io < 4; ++io) {
        WAITVM(4); __builtin_amdgcn_s_barrier(); STG(2, 0);  COMPUTE(0);
        WAITVM(4); __builtin_amdgcn_s_barrier(); STG(0, 32); COMPUTE(1);
        WAITVM(4); __builtin_amdgcn_s_barrier(); STG(1, 64); COMPUTE(2);
        pa0 += 96; pa1 += 96; pb0 += 96; pb1 += 96;
    }
    WAITVM(4); __builtin_amdgcn_s_barrier(); STG(2, 0);  COMPUTE(0);
    WAITVM(4); __builtin_amdgcn_s_barrier(); STG(0, 32); COMPUTE(1);
    WAITVM(4); __builtin_amdgcn_s_barrier(); COMPUTE(2);
    WAITVM(0); __builtin_amdgcn_s_barrier(); COMPUTE(0);
#undef STG
#undef COMPUTE

    // column-term r[j] for the direct store (depends on n only)
    float rj[4];
    #pragma unroll
    for (int n = 0; n < 4; ++n) rj[n] = rvec[j0 + wc * 64 + n * 16 + lrow];

    const int diag = (it == jt);
    #pragma unroll
    for (int m = 0; m < 4; ++m)
        #pragma unroll
        for (int n = 0; n < 4; ++n)
            #pragma unroll
            for (int rr = 0; rr < 4; ++rr) {
                const int i = i0 + wr * 64 + m * 16 + g * 4 + rr;
                const int j = j0 + wc * 64 + n * 16 + lrow;
                C[(size_t)i * NB + j] = f2bf_rne(acc[m][n][rr] + rj[n]);
            }

    if (!diag) {
        float* fsm = (float*)smem_raw;
        #pragma unroll
        for (int p = 0; p < 2; ++p) {
            __syncthreads();
            if (wc == p) {
                #pragma unroll
                for (int m = 0; m < 4; ++m)
                    #pragma unroll
                    for (int n = 0; n < 4; ++n) {
                        const int jl = n * 16 + lrow;
                        const int ilocb = wr * 64 + m * 16 + g * 4;
                        *(f32x4*)&fsm[jl * 128 + (ilocb ^ ((jl & 7) << 2))] = acc[m][n];
                    }
            }
            __syncthreads();
            #pragma unroll
            for (int rep = 0; rep < 8; ++rep) {
                const int idx = rep * 256 + t;
                const int jl = idx >> 5, ic4 = (idx & 31) * 4;
                f32x4 v = *(const f32x4*)&fsm[jl * 128 + (ic4 ^ ((jl & 7) << 2))];
                const f32x4 rv4 = *(const f32x4*)&rvec[i0 + ic4];   // row term r[i]
                u16x4 h;
                h[0] = f2bf_rne(v[0] + rv4[0]); h[1] = f2bf_rne(v[1] + rv4[1]);
                h[2] = f2bf_rne(v[2] + rv4[2]); h[3] = f2bf_rne(v[3] + rv4[3]);
                *(u16x4*)&C[(size_t)(j0 + p * 64 + jl) * NB + i0 + ic4] = h;
            }
        }
    }
}

// ---- fused top-k + gathered diffs: one wave per row, register-resident ----
// scores bf16; key = (sortable_bf16 << 12) | (4095 - idx): one u32 max does
// value-compare AND exact lowest-index tie-break; winner unique by construction
__global__ __launch_bounds__(256) void topk_diffs_kernel(
    const unsigned short* __restrict__ attn, const float* __restrict__ proj,
    double* __restrict__ acc)
{
    const int t = threadIdx.x, lane = t & 63, w = t >> 6;
    const int b = blockIdx.x * 4 + w;
    const unsigned short* rowsrc = attn + (size_t)b * NB;

    // load 64 bf16 (8 x 16B), pack to sortable keys; mask self to 0
    unsigned rr[64];
    #pragma unroll
    for (int j = 0; j < 8; ++j) {
        const uint4 v = *(const uint4*)(rowsrc + lane * 64 + j * 8);
        #pragma unroll
        for (int c = 0; c < 4; ++c) {
            const unsigned pair = ((const unsigned*)&v)[c];
            #pragma unroll
            for (int hh = 0; hh < 2; ++hh) {
                const unsigned u = (hh ? (pair >> 16) : pair) & 0xFFFFu;
                const unsigned s = (u & 0x8000u) ? (~u & 0xFFFFu) : (u | 0x8000u);
                const int e = lane * 64 + j * 8 + c * 2 + hh;
                rr[j * 8 + c * 2 + hh] = (e == b) ? 0u : ((s << 12) | (unsigned)(4095 - e));
            }
        }
    }

#define BUILD(Q, CV) { \
    CV = 0u; \
    _Pragma("unroll") \
    for (int j2 = 0; j2 < 16; ++j2) CV = max(CV, rr[(Q) * 16 + j2]); }

    unsigned cv0, cv1, cv2, cv3;
    BUILD(0, cv0) BUILD(1, cv1) BUILD(2, cv2) BUILD(3, cv3)

    float s1 = 0.f, s2 = 0.f;
    float prev[8];

    for (int k = 0; k < NK; ++k) {
        unsigned bv = max(max(cv0, cv1), max(cv2, cv3));
        #pragma unroll
        for (int o = 1; o <= 32; o <<= 1)
            bv = max(bv, (unsigned)__shfl_xor((int)bv, o, 64));
        // bv is now the global winner key in ALL lanes
        const int idx = 4095 - (int)(bv & 0xFFFu);

        // gather proj row idx (issues early; latency hides under rescan)
        const float* pp = proj + (size_t)idx * 512 + lane * 8;
        const f32x4 a0 = *(const f32x4*)pp;
        const f32x4 a1 = *(const f32x4*)(pp + 4);
        float cur[8] = {a0[0], a0[1], a0[2], a0[3], a1[0], a1[1], a1[2], a1[3]};
        if (k) {
            #pragma unroll
            for (int j = 0; j < 8; ++j) { const float d = cur[j] - prev[j]; s1 += d * d; }
        }
        if (lane < 63) {
            const f32x4 n0 = *(const f32x4*)(pp + 8);
            const f32x4 n1 = *(const f32x4*)(pp + 12);
            const float nxt[8] = {n0[0], n0[1], n0[2], n0[3], n1[0], n1[1], n1[2], n1[3]};
            #pragma unroll
            for (int j = 0; j < 8; ++j) { const float d = nxt[j] - cur[j]; s2 += d * d; }
        }
        #pragma unroll
        for (int j = 0; j < 8; ++j) prev[j] = cur[j];

        // invalidate + rescan winner's chunk (uniform flow; key equality is unique)
#define INVSCAN(Q, CV) { \
    _Pragma("unroll") \
    for (int j2 = 0; j2 < 16; ++j2) if (rr[(Q) * 16 + j2] == bv) rr[(Q) * 16 + j2] = 0u; \
    BUILD(Q, CV) }

        switch ((idx & 63) >> 4) {                // wave-uniform chunk select
            case 0: INVSCAN(0, cv0) break;
            case 1: INVSCAN(1, cv1) break;
            case 2: INVSCAN(2, cv2) break;
            default: INVSCAN(3, cv3) break;
        }
#undef INVSCAN
    }
#undef BUILD

    #pragma unroll
    for (int o = 32; o > 0; o >>= 1) { s1 += __shfl_down(s1, o, 64); s2 += __shfl_down(s2, o, 64); }
    if (lane == 0) {
        const size_t slot = (size_t)(blockIdx.x & 31) * 8;
        atomicAdd(&acc[(size_t)32 * 8 + slot], (double)s1);
        atomicAdd(&acc[(size_t)64 * 8 + slot], (double)s2);
    }
}

// ---------------- finalize loss ----------------
__global__ void finalize_kernel(const double* __restrict__ acc, float* __restrict__ out) {
    if (threadIdx.x == 0) {
        double s0 = 0.0, s1 = 0.0, s2 = 0.0;
        #pragma unroll
        for (int i = 0; i < 32; ++i) {
            s0 += acc[(size_t)i * 8];
            s1 += acc[(size_t)(32 + i) * 8];
            s2 += acc[(size_t)(64 + i) * 8];
        }
        out[0] = (float)(s0 / 2097152.0 + s1 / 31457280.0 + s2 / 33030144.0);
    }
}

extern "C" void kernel_launch(void* const* d_in, const int* in_sizes, int n_in,
                              void* d_out, int out_size, void* d_ws, size_t ws_size,
                              hipStream_t stream) {
    const float* x    = (const float*)d_in[0];
    const float* Wemb = (const float*)d_in[1];
    const float* bemb = (const float*)d_in[2];
    const float* Wp   = (const float*)d_in[3];
    const float* bp   = (const float*)d_in[4];
    float* out  = (float*)d_out;
    float* proj = out + 1;                       // x_rec_proj, B*S*F floats

    char* ws = (char*)d_ws;
    _Float16* X16 = (_Float16*)ws;                               // 4 MB
    _Float16* Y16 = (_Float16*)(ws + ((size_t)4 << 20));         // 4 MB
    unsigned short* attn = (unsigned short*)(ws + ((size_t)8 << 20));  // 32 MB (bf16)
    float*  cst   = (float*)(ws + ((size_t)40 << 20));           // 256 floats
    float*  rvec  = (float*)(ws + ((size_t)40 << 20) + 4096);    // 16 KB
    double* acc   = (double*)(ws + ((size_t)40 << 20) + 65536);  // 96 slots x 64B

    hipMemsetAsync(acc, 0, 96 * 8 * sizeof(double), stream);
    consts_kernel<<<1, 64, 0, stream>>>(Wemb, bemb, Wp, bp, cst);
    prep_kernel<<<NB / 4, 256, 0, stream>>>(x, cst, X16, Y16, proj, rvec, acc);
    attn_gemm_kernel<<<(32 * 33) / 2, 256, 0, stream>>>(X16, Y16, rvec, attn);
    topk_diffs_kernel<<<NB / 4, 256, 0, stream>>>(attn, proj, acc);
    finalize_kernel<<<1, 64, 0, stream>>>(acc, out);
}

// Round 14
// 75.173 us; speedup vs baseline: 1.5294x; 1.0529x over previous
//
#include <hip/hip_runtime.h>
#include <math.h>

#define NB 4096   // batch
#define NS 64     // seq
#define NF 8      // feat
#define ND 64     // d_model
#define KL 512    // GEMM K = NS*NF (rank-8 trick)
#define NK 16     // top-k

typedef _Float16 half8 __attribute__((ext_vector_type(8)));
typedef float    f32x4 __attribute__((ext_vector_type(4)));
typedef unsigned short u16x4 __attribute__((ext_vector_type(4)));

#define GLD16(src, dst) \
  __builtin_amdgcn_global_load_lds((const __attribute__((address_space(1))) void*)(src), \
                                   (__attribute__((address_space(3))) void*)(dst), 16, 0, 0)

#define WAITVM(N) asm volatile("s_waitcnt vmcnt(" #N ")" ::: "memory")

__device__ __forceinline__ unsigned short f2bf_rne(float f) {
    unsigned v = __float_as_uint(f);
    return (unsigned short)((v + 0x7FFFu + ((v >> 16) & 1u)) >> 16);
}

// ---------------- block reduce helper ----------------
__device__ __forceinline__ float blk_reduce(float v, float* red) {
    #pragma unroll
    for (int o = 32; o > 0; o >>= 1) v += __shfl_down(v, o, 64);
    const int t = threadIdx.x;
    __syncthreads();
    if ((t & 63) == 0) red[t >> 6] = v;
    __syncthreads();
    float r = 0.f;
    if (t == 0) r = red[0] + red[1] + red[2] + red[3];
    return r;
}

// ---- consts: G = We@We^T, M = We@Wp, u = We@be, c8 = be@Wp + bp; also zero acc ----
__global__ __launch_bounds__(64) void consts_kernel(
    const float* __restrict__ Wemb, const float* __restrict__ bemb,
    const float* __restrict__ Wp, const float* __restrict__ bp,
    float* __restrict__ cst, double* __restrict__ acc)
{
    __shared__ float sWe[NF * ND];   // [f][d]
    __shared__ float sWp[ND * NF];   // [d][f]
    __shared__ float sbe[ND];
    __shared__ float sbp[NF];
    const int t = threadIdx.x;
    // zero the 96 x 8 double accumulator region (replaces hipMemsetAsync node)
    #pragma unroll
    for (int i = 0; i < 12; ++i) acc[t + i * 64] = 0.0;
    #pragma unroll
    for (int i = 0; i < 8; ++i) { sWe[t + i * 64] = Wemb[t + i * 64]; sWp[t + i * 64] = Wp[t + i * 64]; }
    sbe[t] = bemb[t];
    if (t < NF) sbp[t] = bp[t];
    __syncthreads();
    const int f = t >> 3, f2 = t & 7;
    float g = 0.f, m = 0.f;
    #pragma unroll
    for (int d = 0; d < ND; ++d) {
        g += sWe[f * ND + d] * sWe[f2 * ND + d];
        m += sWe[f * ND + d] * sWp[d * NF + f2];
    }
    cst[t] = g;          // G[f][f2]
    cst[64 + t] = m;     // M[f][f2]
    if (t < NF) {
        float uu = 0.f, cc = 0.f;
        #pragma unroll
        for (int d = 0; d < ND; ++d) {
            uu += sWe[t * ND + d] * sbe[d];
            cc += sbe[d] * sWp[d * NF + t];
        }
        cst[128 + t] = uu;            // u[f]
        cst[136 + t] = cc + sbp[t];   // c8[f]
    }
}

// ---- prep: X16=fp16(x), Y16=fp16(x@G), proj=x@M+c8, r[b]=sum_s x.u, term1 ----
__global__ __launch_bounds__(256) void prep_kernel(
    const float* __restrict__ x, const float* __restrict__ cst,
    _Float16* __restrict__ X16, _Float16* __restrict__ Y16,
    float* __restrict__ proj, float* __restrict__ r, double* __restrict__ acc)
{
    __shared__ float sG[64], sM[64], su[8], sc[8];
    __shared__ float red[4];
    const int t = threadIdx.x, lane = t & 63, w = t >> 6;
    if (t < 64) sG[t] = cst[t];
    else if (t < 128) sM[t - 64] = cst[t];
    else if (t < 136) su[t - 128] = cst[t];
    else if (t < 144) sc[t - 136] = cst[t];
    __syncthreads();
    const int b = blockIdx.x * 4 + w;
    const size_t base = (size_t)b * KL + lane * 8;
    const f32x4 x0 = *(const f32x4*)&x[base];
    const f32x4 x1 = *(const f32x4*)&x[base + 4];
    float xv[8] = {x0[0], x0[1], x0[2], x0[3], x1[0], x1[1], x1[2], x1[3]};
    float yv[8], pv[8];
    #pragma unroll
    for (int f2 = 0; f2 < 8; ++f2) { yv[f2] = 0.f; pv[f2] = sc[f2]; }
    #pragma unroll
    for (int f = 0; f < 8; ++f)
        #pragma unroll
        for (int f2 = 0; f2 < 8; ++f2) {
            yv[f2] += xv[f] * sG[f * 8 + f2];
            pv[f2] += xv[f] * sM[f * 8 + f2];
        }
    half8 hx, hy;
    #pragma unroll
    for (int j = 0; j < 8; ++j) { hx[j] = (_Float16)xv[j]; hy[j] = (_Float16)yv[j]; }
    *(half8*)&X16[base] = hx;
    *(half8*)&Y16[base] = hy;
    *(f32x4*)&proj[base] = (f32x4){pv[0], pv[1], pv[2], pv[3]};
    *(f32x4*)&proj[base + 4] = (f32x4){pv[4], pv[5], pv[6], pv[7]};
    float rv = 0.f;
    #pragma unroll
    for (int f = 0; f < 8; ++f) rv += xv[f] * su[f];
    #pragma unroll
    for (int o = 32; o > 0; o >>= 1) rv += __shfl_down(rv, o, 64);
    if (lane == 0) r[b] = rv;
    float s1 = 0.f;
    #pragma unroll
    for (int j = 0; j < 8; ++j) { const float d = pv[j] - xv[j]; s1 += d * d; }
    const float tot = blk_reduce(s1, red);
    if (t == 0) atomicAdd(&acc[(size_t)(blockIdx.x & 31) * 8], (double)tot);
}

// ---- dot = X @ Y^T (K=512) fp16 MFMA, lower-tri, 3-buf depth-2 pipeline ----
// epilogue: C_bf16[i][j] = bf16(dot + r[j]); mirror C_bf16[j][i] = bf16(dot + r[i])
__global__ __launch_bounds__(256) void attn_gemm_kernel(
    const _Float16* __restrict__ Xf, const _Float16* __restrict__ Yf,
    const float* __restrict__ rvec, unsigned short* __restrict__ C)
{
    __shared__ __align__(16) char smem_raw[49152];
    _Float16* smem = (_Float16*)smem_raw;

    const int t = threadIdx.x;
    const int lane = t & 63, wid = t >> 6;
    const int wr = wid >> 1, wc = wid & 1;

    const int bid0 = blockIdx.x;
    const int bid = (bid0 & 7) * 66 + (bid0 >> 3);

    int it = (int)((sqrtf(8.0f * (float)bid + 1.0f) - 1.0f) * 0.5f);
    while ((it + 1) * (it + 2) / 2 <= bid) ++it;
    while (it * (it + 1) / 2 > bid) --it;
    const int jt = bid - it * (it + 1) / 2;
    const int i0 = it * 128, j0 = jt * 128;

    f32x4 acc[4][4];
    #pragma unroll
    for (int m = 0; m < 4; ++m)
        #pragma unroll
        for (int n = 0; n < 4; ++n) acc[m][n] = (f32x4){0.f, 0.f, 0.f, 0.f};

    const int lrow = lane & 15, g = lane >> 4;
    const int ksw = (g ^ ((lrow >> 1) & 3)) * 8;

    const int c0 = t, c1 = t + 256;
    const int r0 = c0 >> 2, r1 = c1 >> 2;
    const int cs0 = ((c0 & 3) ^ ((r0 >> 1) & 3)) * 8;
    const int cs1 = ((c1 & 3) ^ ((r1 >> 1) & 3)) * 8;
    const _Float16* pa0 = Xf + (size_t)(i0 + r0) * KL + cs0;
    const _Float16* pa1 = Xf + (size_t)(i0 + r1) * KL + cs1;
    const _Float16* pb0 = Yf + (size_t)(j0 + r0) * KL + cs0;
    const _Float16* pb1 = Yf + (size_t)(j0 + r1) * KL + cs1;
    _Float16* d0 = smem + c0 * 8;
    _Float16* d1 = smem + c1 * 8;

#define STG(BUF, KH) { \
    GLD16(pa0 + (KH), d0 + (BUF) * 8192); \
    GLD16(pa1 + (KH), d1 + (BUF) * 8192); \
    GLD16(pb0 + (KH), d0 + (BUF) * 8192 + 4096); \
    GLD16(pb1 + (KH), d1 + (BUF) * 8192 + 4096); }

    const int roA = wr * 2048 + lrow * 32 + ksw;
    const int roB = wc * 2048 + lrow * 32 + ksw;

#define COMPUTE(BUF) { \
    const _Float16* sA = smem + (BUF) * 8192; \
    const _Float16* sB = sA + 4096; \
    half8 fa[4], fb[4]; \
    _Pragma("unroll") \
    for (int m = 0; m < 4; ++m) { \
        fa[m] = *(const half8*)&sA[roA + m * 512]; \
        fb[m] = *(const half8*)&sB[roB + m * 512]; \
    } \
    __builtin_amdgcn_s_setprio(1); \
    _Pragma("unroll") \
    for (int m = 0; m < 4; ++m) \
        _Pragma("unroll") \
        for (int n = 0; n < 4; ++n) \
            acc[m][n] = __builtin_amdgcn_mfma_f32_16x16x32_f16(fa[m], fb[n], acc[m][n], 0, 0, 0); \
    __builtin_amdgcn_s_setprio(0); }

    STG(0, 0); STG(1, 32);
    pa0 += 64; pa1 += 64; pb0 += 64; pb1 += 64;
    #pragma unroll 1
    for (int io = 0; io < 4; ++io) {
        WAITVM(4); __builtin_amdgcn_s_barrier(); STG(2, 0);  COMPUTE(0);
        WAITVM(4); __builtin_amdgcn_s_barrier(); STG(0, 32); COMPUTE(1);
        WAITVM(4); __builtin_amdgcn_s_barrier(); STG(1, 64); COMPUTE(2);
        pa0 += 96; pa1 += 96; pb0 += 96; pb1 += 96;
    }
    WAITVM(4); __builtin_amdgcn_s_barrier(); STG(2, 0);  COMPUTE(0);
    WAITVM(4); __builtin_amdgcn_s_barrier(); STG(0, 32); COMPUTE(1);
    WAITVM(4); __builtin_amdgcn_s_barrier(); COMPUTE(2);
    WAITVM(0); __builtin_amdgcn_s_barrier(); COMPUTE(0);
#undef STG
#undef COMPUTE

    // column-term r[j] for the direct store (depends on n only)
    float rj[4];
    #pragma unroll
    for (int n = 0; n < 4; ++n) rj[n] = rvec[j0 + wc * 64 + n * 16 + lrow];

    const int diag = (it == jt);
    #pragma unroll
    for (int m = 0; m < 4; ++m)
        #pragma unroll
        for (int n = 0; n < 4; ++n)
            #pragma unroll
            for (int rr = 0; rr < 4; ++rr) {
                const int i = i0 + wr * 64 + m * 16 + g * 4 + rr;
                const int j = j0 + wc * 64 + n * 16 + lrow;
                C[(size_t)i * NB + j] = f2bf_rne(acc[m][n][rr] + rj[n]);
            }

    if (!diag) {
        float* fsm = (float*)smem_raw;
        #pragma unroll
        for (int p = 0; p < 2; ++p) {
            __syncthreads();
            if (wc == p) {
                #pragma unroll
                for (int m = 0; m < 4; ++m)
                    #pragma unroll
                    for (int n = 0; n < 4; ++n) {
                        const int jl = n * 16 + lrow;
                        const int ilocb = wr * 64 + m * 16 + g * 4;
                        *(f32x4*)&fsm[jl * 128 + (ilocb ^ ((jl & 7) << 2))] = acc[m][n];
                    }
            }
            __syncthreads();
            #pragma unroll
            for (int rep = 0; rep < 8; ++rep) {
                const int idx = rep * 256 + t;
                const int jl = idx >> 5, ic4 = (idx & 31) * 4;
                f32x4 v = *(const f32x4*)&fsm[jl * 128 + (ic4 ^ ((jl & 7) << 2))];
                const f32x4 rv4 = *(const f32x4*)&rvec[i0 + ic4];   // row term r[i]
                u16x4 h;
                h[0] = f2bf_rne(v[0] + rv4[0]); h[1] = f2bf_rne(v[1] + rv4[1]);
                h[2] = f2bf_rne(v[2] + rv4[2]); h[3] = f2bf_rne(v[3] + rv4[3]);
                *(u16x4*)&C[(size_t)(j0 + p * 64 + jl) * NB + i0 + ic4] = h;
            }
        }
    }
}

// ---- fused top-k + gathered diffs: one wave per row, register-resident ----
// INTERLEAVED granule ownership: lane owns e = j*512 + lane*8 + c (j=0..7, c=0..7)
// -> every 16B load is lane-consecutive = fully coalesced (1 KB/instruction).
// key = (sortable_bf16 << 12) | (4095 - idx): u32 max = value + exact min-index ties.
__global__ __launch_bounds__(256) void topk_diffs_kernel(
    const unsigned short* __restrict__ attn, const float* __restrict__ proj,
    double* __restrict__ acc)
{
    const int t = threadIdx.x, lane = t & 63, w = t >> 6;
    const int b = blockIdx.x * 4 + w;
    const unsigned short* rowsrc = attn + (size_t)b * NB;

    // coalesced load: 8 x 16B per lane; pack to sortable keys; mask self to 0
    unsigned rr[64];
    #pragma unroll
    for (int j = 0; j < 8; ++j) {
        const uint4 v = *(const uint4*)(rowsrc + j * 512 + lane * 8);
        #pragma unroll
        for (int c = 0; c < 4; ++c) {
            const unsigned pair = ((const unsigned*)&v)[c];
            #pragma unroll
            for (int hh = 0; hh < 2; ++hh) {
                const unsigned u = (hh ? (pair >> 16) : pair) & 0xFFFFu;
                const unsigned s = (u & 0x8000u) ? (~u & 0xFFFFu) : (u | 0x8000u);
                const int e = j * 512 + lane * 8 + c * 2 + hh;
                rr[j * 8 + c * 2 + hh] = (e == b) ? 0u : ((s << 12) | (unsigned)(4095 - e));
            }
        }
    }

#define BUILD(Q, CV) { \
    CV = 0u; \
    _Pragma("unroll") \
    for (int j2 = 0; j2 < 16; ++j2) CV = max(CV, rr[(Q) * 16 + j2]); }

    unsigned cv0, cv1, cv2, cv3;
    BUILD(0, cv0) BUILD(1, cv1) BUILD(2, cv2) BUILD(3, cv3)

    float s1 = 0.f, s2 = 0.f;
    float prev[8];

    for (int k = 0; k < NK; ++k) {
        unsigned bv = max(max(cv0, cv1), max(cv2, cv3));
        #pragma unroll
        for (int o = 1; o <= 32; o <<= 1)
            bv = max(bv, (unsigned)__shfl_xor((int)bv, o, 64));
        // bv = global winner key in ALL lanes
        const int idx = 4095 - (int)(bv & 0xFFFu);

        // gather proj row idx (issues early; latency hides under rescan)
        const float* pp = proj + (size_t)idx * 512 + lane * 8;
        const f32x4 a0 = *(const f32x4*)pp;
        const f32x4 a1 = *(const f32x4*)(pp + 4);
        float cur[8] = {a0[0], a0[1], a0[2], a0[3], a1[0], a1[1], a1[2], a1[3]};
        if (k) {
            #pragma unroll
            for (int j = 0; j < 8; ++j) { const float d = cur[j] - prev[j]; s1 += d * d; }
        }
        if (lane < 63) {
            const f32x4 n0 = *(const f32x4*)(pp + 8);
            const f32x4 n1 = *(const f32x4*)(pp + 12);
            const float nxt[8] = {n0[0], n0[1], n0[2], n0[3], n1[0], n1[1], n1[2], n1[3]};
            #pragma unroll
            for (int j = 0; j < 8; ++j) { const float d = nxt[j] - cur[j]; s2 += d * d; }
        }
        #pragma unroll
        for (int j = 0; j < 8; ++j) prev[j] = cur[j];

        // invalidate + rescan winner's chunk (uniform flow; key equality unique)
        // chunk q = idx>>10  (e = j*512 + ..., j = idx>>9, q = j>>1)
#define INVSCAN(Q, CV) { \
    _Pragma("unroll") \
    for (int j2 = 0; j2 < 16; ++j2) if (rr[(Q) * 16 + j2] == bv) rr[(Q) * 16 + j2] = 0u; \
    BUILD(Q, CV) }

        switch ((idx >> 10) & 3) {                // wave-uniform chunk select
            case 0: INVSCAN(0, cv0) break;
            case 1: INVSCAN(1, cv1) break;
            case 2: INVSCAN(2, cv2) break;
            default: INVSCAN(3, cv3) break;
        }
#undef INVSCAN
    }
#undef BUILD

    #pragma unroll
    for (int o = 32; o > 0; o >>= 1) { s1 += __shfl_down(s1, o, 64); s2 += __shfl_down(s2, o, 64); }
    if (lane == 0) {
        const size_t slot = (size_t)(blockIdx.x & 31) * 8;
        atomicAdd(&acc[(size_t)32 * 8 + slot], (double)s1);
        atomicAdd(&acc[(size_t)64 * 8 + slot], (double)s2);
    }
}

// ---------------- finalize loss ----------------
__global__ void finalize_kernel(const double* __restrict__ acc, float* __restrict__ out) {
    if (threadIdx.x == 0) {
        double s0 = 0.0, s1 = 0.0, s2 = 0.0;
        #pragma unroll
        for (int i = 0; i < 32; ++i) {
            s0 += acc[(size_t)i * 8];
            s1 += acc[(size_t)(32 + i) * 8];
            s2 += acc[(size_t)(64 + i) * 8];
        }
        out[0] = (float)(s0 / 2097152.0 + s1 / 31457280.0 + s2 / 33030144.0);
    }
}

extern "C" void kernel_launch(void* const* d_in, const int* in_sizes, int n_in,
                              void* d_out, int out_size, void* d_ws, size_t ws_size,
                              hipStream_t stream) {
    const float* x    = (const float*)d_in[0];
    const float* Wemb = (const float*)d_in[1];
    const float* bemb = (const float*)d_in[2];
    const float* Wp   = (const float*)d_in[3];
    const float* bp   = (const float*)d_in[4];
    float* out  = (float*)d_out;
    float* proj = out + 1;                       // x_rec_proj, B*S*F floats

    char* ws = (char*)d_ws;
    _Float16* X16 = (_Float16*)ws;                               // 4 MB
    _Float16* Y16 = (_Float16*)(ws + ((size_t)4 << 20));         // 4 MB
    unsigned short* attn = (unsigned short*)(ws + ((size_t)8 << 20));  // 32 MB (bf16)
    float*  cst   = (float*)(ws + ((size_t)40 << 20));           // 256 floats
    float*  rvec  = (float*)(ws + ((size_t)40 << 20) + 4096);    // 16 KB
    double* acc   = (double*)(ws + ((size_t)40 << 20) + 65536);  // 96 slots x 64B

    consts_kernel<<<1, 64, 0, stream>>>(Wemb, bemb, Wp, bp, cst, acc);
    prep_kernel<<<NB / 4, 256, 0, stream>>>(x, cst, X16, Y16, proj, rvec, acc);
    attn_gemm_kernel<<<(32 * 33) / 2, 256, 0, stream>>>(X16, Y16, rvec, attn);
    topk_diffs_kernel<<<NB / 4, 256, 0, stream>>>(attn, proj, acc);
    finalize_kernel<<<1, 64, 0, stream>>>(acc, out);
}

// Round 15
// 72.430 us; speedup vs baseline: 1.5873x; 1.0379x over previous
//
#include <hip/hip_runtime.h>
#include <math.h>

#define NB 4096   // batch
#define NS 64     // seq
#define NF 8      // feat
#define ND 64     // d_model
#define KL 512    // GEMM K = NS*NF (rank-8 trick)
#define NK 16     // top-k

typedef _Float16 half8 __attribute__((ext_vector_type(8)));
typedef float    f32x4 __attribute__((ext_vector_type(4)));

#define GLD16(src, dst) \
  __builtin_amdgcn_global_load_lds((const __attribute__((address_space(1))) void*)(src), \
                                   (__attribute__((address_space(3))) void*)(dst), 16, 0, 0)

#define WAITVM(N) asm volatile("s_waitcnt vmcnt(" #N ")" ::: "memory")

__device__ __forceinline__ unsigned short f2bf_rne(float f) {
    unsigned v = __float_as_uint(f);
    return (unsigned short)((v + 0x7FFFu + ((v >> 16) & 1u)) >> 16);
}
// packed candidate key: sortable bf16 (16b) << 12 | (4095 - col); u32 max == exact
// (value, lowest-col) order; key 0 = -inf sentinel
__device__ __forceinline__ unsigned bf16key(float v, int col) {
    const unsigned u = f2bf_rne(v);
    const unsigned s = (u & 0x8000u) ? (~u & 0xFFFFu) : (u | 0x8000u);
    return (s << 12) | (unsigned)(4095 - col);
}

// top-2 maintenance (M1 >= M2 invariant)
#define UPD2(M1, M2, K) { const unsigned k_ = (K); \
    if (k_ > M1) { M2 = M1; M1 = k_; } else if (k_ > M2) M2 = k_; }
// merge this lane's (M1,M2) with lane^OFF's pair (both sorted) -> top-2 of union
#define MERGE2(M1, M2, OFF) { \
    const unsigned o1 = (unsigned)__shfl_xor((int)M1, OFF, 64); \
    const unsigned o2 = (unsigned)__shfl_xor((int)M2, OFF, 64); \
    const unsigned hi = M1 > o1 ? M1 : o1; \
    const unsigned lo = M1 > o1 ? o1 : M1; \
    const unsigned mx = M2 > o2 ? M2 : o2; \
    M1 = hi; M2 = lo > mx ? lo : mx; }

// ---------------- block reduce helper ----------------
__device__ __forceinline__ float blk_reduce(float v, float* red) {
    #pragma unroll
    for (int o = 32; o > 0; o >>= 1) v += __shfl_down(v, o, 64);
    const int t = threadIdx.x;
    __syncthreads();
    if ((t & 63) == 0) red[t >> 6] = v;
    __syncthreads();
    float r = 0.f;
    if (t == 0) r = red[0] + red[1] + red[2] + red[3];
    return r;
}

// ---- consts: G = We@We^T, M = We@Wp, u = We@be, c8 = be@Wp + bp; also zero acc ----
__global__ __launch_bounds__(64) void consts_kernel(
    const float* __restrict__ Wemb, const float* __restrict__ bemb,
    const float* __restrict__ Wp, const float* __restrict__ bp,
    float* __restrict__ cst, double* __restrict__ acc)
{
    __shared__ float sWe[NF * ND];   // [f][d]
    __shared__ float sWp[ND * NF];   // [d][f]
    __shared__ float sbe[ND];
    __shared__ float sbp[NF];
    const int t = threadIdx.x;
    #pragma unroll
    for (int i = 0; i < 12; ++i) acc[t + i * 64] = 0.0;   // zero 96x8 acc slots
    #pragma unroll
    for (int i = 0; i < 8; ++i) { sWe[t + i * 64] = Wemb[t + i * 64]; sWp[t + i * 64] = Wp[t + i * 64]; }
    sbe[t] = bemb[t];
    if (t < NF) sbp[t] = bp[t];
    __syncthreads();
    const int f = t >> 3, f2 = t & 7;
    float g = 0.f, m = 0.f;
    #pragma unroll
    for (int d = 0; d < ND; ++d) {
        g += sWe[f * ND + d] * sWe[f2 * ND + d];
        m += sWe[f * ND + d] * sWp[d * NF + f2];
    }
    cst[t] = g;          // G[f][f2]
    cst[64 + t] = m;     // M[f][f2]
    if (t < NF) {
        float uu = 0.f, cc = 0.f;
        #pragma unroll
        for (int d = 0; d < ND; ++d) {
            uu += sWe[t * ND + d] * sbe[d];
            cc += sbe[d] * sWp[d * NF + t];
        }
        cst[128 + t] = uu;            // u[f]
        cst[136 + t] = cc + sbp[t];   // c8[f]
    }
}

// ---- prep: X16=fp16(x), Y16=fp16(x@G), proj=x@M+c8, r[b]=sum_s x.u, term1 ----
__global__ __launch_bounds__(256) void prep_kernel(
    const float* __restrict__ x, const float* __restrict__ cst,
    _Float16* __restrict__ X16, _Float16* __restrict__ Y16,
    float* __restrict__ proj, float* __restrict__ r, double* __restrict__ acc)
{
    __shared__ float sG[64], sM[64], su[8], sc[8];
    __shared__ float red[4];
    const int t = threadIdx.x, lane = t & 63, w = t >> 6;
    if (t < 64) sG[t] = cst[t];
    else if (t < 128) sM[t - 64] = cst[t];
    else if (t < 136) su[t - 128] = cst[t];
    else if (t < 144) sc[t - 136] = cst[t];
    __syncthreads();
    const int b = blockIdx.x * 4 + w;
    const size_t base = (size_t)b * KL + lane * 8;
    const f32x4 x0 = *(const f32x4*)&x[base];
    const f32x4 x1 = *(const f32x4*)&x[base + 4];
    float xv[8] = {x0[0], x0[1], x0[2], x0[3], x1[0], x1[1], x1[2], x1[3]};
    float yv[8], pv[8];
    #pragma unroll
    for (int f2 = 0; f2 < 8; ++f2) { yv[f2] = 0.f; pv[f2] = sc[f2]; }
    #pragma unroll
    for (int f = 0; f < 8; ++f)
        #pragma unroll
        for (int f2 = 0; f2 < 8; ++f2) {
            yv[f2] += xv[f] * sG[f * 8 + f2];
            pv[f2] += xv[f] * sM[f * 8 + f2];
        }
    half8 hx, hy;
    #pragma unroll
    for (int j = 0; j < 8; ++j) { hx[j] = (_Float16)xv[j]; hy[j] = (_Float16)yv[j]; }
    *(half8*)&X16[base] = hx;
    *(half8*)&Y16[base] = hy;
    *(f32x4*)&proj[base] = (f32x4){pv[0], pv[1], pv[2], pv[3]};
    *(f32x4*)&proj[base + 4] = (f32x4){pv[4], pv[5], pv[6], pv[7]};
    float rv = 0.f;
    #pragma unroll
    for (int f = 0; f < 8; ++f) rv += xv[f] * su[f];
    #pragma unroll
    for (int o = 32; o > 0; o >>= 1) rv += __shfl_down(rv, o, 64);
    if (lane == 0) r[b] = rv;
    float s1 = 0.f;
    #pragma unroll
    for (int j = 0; j < 8; ++j) { const float d = pv[j] - xv[j]; s1 += d * d; }
    const float tot = blk_reduce(s1, red);
    if (t == 0) atomicAdd(&acc[(size_t)(blockIdx.x & 31) * 8], (double)tot);
}

// ---- dot = X @ Y^T (K=512) fp16 MFMA, lower-tri, 3-buf depth-2 pipeline ----
// epilogue emits per-(row, 64-col-group) TOP-2 packed candidate keys (no score matrix):
//   direct: rows of i-panel, groups (jt*2+wc); mirror: rows of j-panel, groups (it*2+wr)
__global__ __launch_bounds__(256) void attn_gemm_kernel(
    const _Float16* __restrict__ Xf, const _Float16* __restrict__ Yf,
    const float* __restrict__ rvec, unsigned* __restrict__ cand)
{
    __shared__ __align__(16) char smem_raw[49152];
    _Float16* smem = (_Float16*)smem_raw;

    const int t = threadIdx.x;
    const int lane = t & 63, wid = t >> 6;
    const int wr = wid >> 1, wc = wid & 1;

    const int bid0 = blockIdx.x;
    const int bid = (bid0 & 7) * 66 + (bid0 >> 3);

    int it = (int)((sqrtf(8.0f * (float)bid + 1.0f) - 1.0f) * 0.5f);
    while ((it + 1) * (it + 2) / 2 <= bid) ++it;
    while (it * (it + 1) / 2 > bid) --it;
    const int jt = bid - it * (it + 1) / 2;
    const int i0 = it * 128, j0 = jt * 128;

    f32x4 acc[4][4];
    #pragma unroll
    for (int m = 0; m < 4; ++m)
        #pragma unroll
        for (int n = 0; n < 4; ++n) acc[m][n] = (f32x4){0.f, 0.f, 0.f, 0.f};

    const int lrow = lane & 15, g = lane >> 4;
    const int ksw = (g ^ ((lrow >> 1) & 3)) * 8;

    const int c0 = t, c1 = t + 256;
    const int r0 = c0 >> 2, r1 = c1 >> 2;
    const int cs0 = ((c0 & 3) ^ ((r0 >> 1) & 3)) * 8;
    const int cs1 = ((c1 & 3) ^ ((r1 >> 1) & 3)) * 8;
    const _Float16* pa0 = Xf + (size_t)(i0 + r0) * KL + cs0;
    const _Float16* pa1 = Xf + (size_t)(i0 + r1) * KL + cs1;
    const _Float16* pb0 = Yf + (size_t)(j0 + r0) * KL + cs0;
    const _Float16* pb1 = Yf + (size_t)(j0 + r1) * KL + cs1;
    _Float16* d0 = smem + c0 * 8;
    _Float16* d1 = smem + c1 * 8;

#define STG(BUF, KH) { \
    GLD16(pa0 + (KH), d0 + (BUF) * 8192); \
    GLD16(pa1 + (KH), d1 + (BUF) * 8192); \
    GLD16(pb0 + (KH), d0 + (BUF) * 8192 + 4096); \
    GLD16(pb1 + (KH), d1 + (BUF) * 8192 + 4096); }

    const int roA = wr * 2048 + lrow * 32 + ksw;
    const int roB = wc * 2048 + lrow * 32 + ksw;

#define COMPUTE(BUF) { \
    const _Float16* sA = smem + (BUF) * 8192; \
    const _Float16* sB = sA + 4096; \
    half8 fa[4], fb[4]; \
    _Pragma("unroll") \
    for (int m = 0; m < 4; ++m) { \
        fa[m] = *(const half8*)&sA[roA + m * 512]; \
        fb[m] = *(const half8*)&sB[roB + m * 512]; \
    } \
    __builtin_amdgcn_s_setprio(1); \
    _Pragma("unroll") \
    for (int m = 0; m < 4; ++m) \
        _Pragma("unroll") \
        for (int n = 0; n < 4; ++n) \
            acc[m][n] = __builtin_amdgcn_mfma_f32_16x16x32_f16(fa[m], fb[n], acc[m][n], 0, 0, 0); \
    __builtin_amdgcn_s_setprio(0); }

    STG(0, 0); STG(1, 32);
    pa0 += 64; pa1 += 64; pb0 += 64; pb1 += 64;
    #pragma unroll 1
    for (int io = 0; io < 4; ++io) {
        WAITVM(4); __builtin_amdgcn_s_barrier(); STG(2, 0);  COMPUTE(0);
        WAITVM(4); __builtin_amdgcn_s_barrier(); STG(0, 32); COMPUTE(1);
        WAITVM(4); __builtin_amdgcn_s_barrier(); STG(1, 64); COMPUTE(2);
        pa0 += 96; pa1 += 96; pb0 += 96; pb1 += 96;
    }
    WAITVM(4); __builtin_amdgcn_s_barrier(); STG(2, 0);  COMPUTE(0);
    WAITVM(4); __builtin_amdgcn_s_barrier(); STG(0, 32); COMPUTE(1);
    WAITVM(4); __builtin_amdgcn_s_barrier(); COMPUTE(2);
    WAITVM(0); __builtin_amdgcn_s_barrier(); COMPUTE(0);
#undef STG
#undef COMPUTE

    // column-term r[j] (depends on n only)
    float rj[4];
    #pragma unroll
    for (int n = 0; n < 4; ++n) rj[n] = rvec[j0 + wc * 64 + n * 16 + lrow];

    const int diag = (it == jt);

    // ---- direct: per-row top-2 over this wave's 64 cols ----
    // row (m,g,rr)'s 64 cols live in the 16 lanes sharing g (lrow 0..15) x n regs
    #pragma unroll
    for (int m = 0; m < 4; ++m)
        #pragma unroll
        for (int rr = 0; rr < 4; ++rr) {
            const int i = i0 + wr * 64 + m * 16 + g * 4 + rr;
            unsigned m1 = 0u, m2 = 0u;
            #pragma unroll
            for (int n = 0; n < 4; ++n) {
                const int j = j0 + wc * 64 + n * 16 + lrow;
                unsigned key = bf16key(acc[m][n][rr] + rj[n], j);
                if (i == j) key = 0u;              // self-mask (diag tiles)
                UPD2(m1, m2, key)
            }
            MERGE2(m1, m2, 1) MERGE2(m1, m2, 2) MERGE2(m1, m2, 4) MERGE2(m1, m2, 8)
            if (lrow == 0) {
                uint2 st; st.x = m1; st.y = m2;
                *(uint2*)(cand + (size_t)i * 128 + (size_t)(jt * 2 + wc) * 2) = st;
            }
        }

    // ---- mirror: per-col top-2 over this wave's 64 rows (off-diag only) ----
    // col (n,lrow)'s 64 rows live in-lane (m,rr) x the 4 lanes sharing lrow (g 0..3)
    if (!diag) {
        #pragma unroll
        for (int n = 0; n < 4; ++n) {
            const int j = j0 + wc * 64 + n * 16 + lrow;
            unsigned m1 = 0u, m2 = 0u;
            #pragma unroll
            for (int m = 0; m < 4; ++m) {
                const f32x4 riv = *(const f32x4*)&rvec[i0 + wr * 64 + m * 16 + g * 4];
                #pragma unroll
                for (int rr = 0; rr < 4; ++rr) {
                    const int i = i0 + wr * 64 + m * 16 + g * 4 + rr;
                    UPD2(m1, m2, bf16key(acc[m][n][rr] + riv[rr], i))
                }
            }
            MERGE2(m1, m2, 16) MERGE2(m1, m2, 32)
            if (g == 0) {
                uint2 st; st.x = m1; st.y = m2;
                *(uint2*)(cand + (size_t)j * 128 + (size_t)(it * 2 + wr) * 2) = st;
            }
        }
    }
}

// ---- fused top-k + gathered diffs: one wave per row, 2 candidate keys per lane ----
__global__ __launch_bounds__(256) void topk_diffs_kernel(
    const unsigned* __restrict__ cand, const float* __restrict__ proj,
    double* __restrict__ acc)
{
    const int t = threadIdx.x, lane = t & 63, w = t >> 6;
    const int b = blockIdx.x * 4 + w;
    const uint2 kk = *(const uint2*)(cand + (size_t)b * 128 + lane * 2);
    unsigned k0 = kk.x, k1 = kk.y;

    float s1 = 0.f, s2 = 0.f;
    float prev[8];

    for (int k = 0; k < NK; ++k) {
        unsigned bv = k0 > k1 ? k0 : k1;
        #pragma unroll
        for (int o = 1; o <= 32; o <<= 1)
            bv = max(bv, (unsigned)__shfl_xor((int)bv, o, 64));
        const int idx = 4095 - (int)(bv & 0xFFFu);   // winner column, all lanes

        // gather proj row idx; lane holds elems [lane*8, lane*8+8)
        const float* pp = proj + (size_t)idx * 512 + lane * 8;
        const f32x4 a0 = *(const f32x4*)pp;
        const f32x4 a1 = *(const f32x4*)(pp + 4);
        float cur[8] = {a0[0], a0[1], a0[2], a0[3], a1[0], a1[1], a1[2], a1[3]};
        if (k) {
            #pragma unroll
            for (int j = 0; j < 8; ++j) { const float d = cur[j] - prev[j]; s1 += d * d; }
        }
        if (lane < 63) {
            const f32x4 n0 = *(const f32x4*)(pp + 8);
            const f32x4 n1 = *(const f32x4*)(pp + 12);
            const float nxt[8] = {n0[0], n0[1], n0[2], n0[3], n1[0], n1[1], n1[2], n1[3]};
            #pragma unroll
            for (int j = 0; j < 8; ++j) { const float d = nxt[j] - cur[j]; s2 += d * d; }
        }
        #pragma unroll
        for (int j = 0; j < 8; ++j) prev[j] = cur[j];

        // invalidate winner (keys are unique)
        if (k0 == bv) k0 = 0u;
        if (k1 == bv) k1 = 0u;
    }

    #pragma unroll
    for (int o = 32; o > 0; o >>= 1) { s1 += __shfl_down(s1, o, 64); s2 += __shfl_down(s2, o, 64); }
    if (lane == 0) {
        const size_t slot = (size_t)(blockIdx.x & 31) * 8;
        atomicAdd(&acc[(size_t)32 * 8 + slot], (double)s1);
        atomicAdd(&acc[(size_t)64 * 8 + slot], (double)s2);
    }
}

// ---------------- finalize loss ----------------
__global__ void finalize_kernel(const double* __restrict__ acc, float* __restrict__ out) {
    if (threadIdx.x == 0) {
        double s0 = 0.0, s1 = 0.0, s2 = 0.0;
        #pragma unroll
        for (int i = 0; i < 32; ++i) {
            s0 += acc[(size_t)i * 8];
            s1 += acc[(size_t)(32 + i) * 8];
            s2 += acc[(size_t)(64 + i) * 8];
        }
        out[0] = (float)(s0 / 2097152.0 + s1 / 31457280.0 + s2 / 33030144.0);
    }
}

extern "C" void kernel_launch(void* const* d_in, const int* in_sizes, int n_in,
                              void* d_out, int out_size, void* d_ws, size_t ws_size,
                              hipStream_t stream) {
    const float* x    = (const float*)d_in[0];
    const float* Wemb = (const float*)d_in[1];
    const float* bemb = (const float*)d_in[2];
    const float* Wp   = (const float*)d_in[3];
    const float* bp   = (const float*)d_in[4];
    float* out  = (float*)d_out;
    float* proj = out + 1;                       // x_rec_proj, B*S*F floats

    char* ws = (char*)d_ws;
    _Float16* X16 = (_Float16*)ws;                               // 4 MB
    _Float16* Y16 = (_Float16*)(ws + ((size_t)4 << 20));         // 4 MB
    unsigned* cand = (unsigned*)(ws + ((size_t)8 << 20));        // 2 MB (4096 x 128 keys)
    float*  cst   = (float*)(ws + ((size_t)10 << 20));           // 256 floats
    float*  rvec  = (float*)(ws + ((size_t)10 << 20) + 4096);    // 16 KB
    double* acc   = (double*)(ws + ((size_t)10 << 20) + 65536);  // 96 slots x 64B

    consts_kernel<<<1, 64, 0, stream>>>(Wemb, bemb, Wp, bp, cst, acc);
    prep_kernel<<<NB / 4, 256, 0, stream>>>(x, cst, X16, Y16, proj, rvec, acc);
    attn_gemm_kernel<<<(32 * 33) / 2, 256, 0, stream>>>(X16, Y16, rvec, cand);
    topk_diffs_kernel<<<NB / 4, 256, 0, stream>>>(cand, proj, acc);
    finalize_kernel<<<1, 64, 0, stream>>>(acc, out);
}